// Round 1
// baseline (167.453 us; speedup 1.0000x reference)
//
#include <hip/hip_runtime.h>
#include <hip/hip_bf16.h>
#include <math.h>

#define BB 65536
#define DD 256
#define KK 10
#define LOG_2PI 1.8378770664093453f

// ---------------------------------------------------------------------------
// Prep kernel: grid = K blocks x D threads.
// Writes interleaved table tab[(d/4)*K + k][8] = {iv[d..d+3], -2*mu*iv[d..d+3]}
// and per-component constant C[k].
// ---------------------------------------------------------------------------
__global__ __launch_bounds__(DD) void gmvae_prep(
    const float* __restrict__ mu_table,
    const float* __restrict__ logvar_table,
    float* __restrict__ tab,   // 2*K*D floats
    float* __restrict__ C)     // K floats
{
    const int k = blockIdx.x;
    const int d = threadIdx.x;
    const float lv = logvar_table[k * DD + d];
    const float m  = mu_table[k * DD + d];
    const float iv = expf(-lv);          // 1/exp(lv); exact 1.0 when lv==0
    const float a  = m * iv;

    const int base = (((d >> 2) * KK) + k) * 8 + (d & 3);
    tab[base]     = iv;
    tab[base + 4] = -2.0f * a;

    // partial for C_k: mu^2*iv + lv
    float p = fmaf(m, a, lv);

    __shared__ float red[4];
    #pragma unroll
    for (int off = 32; off > 0; off >>= 1)
        p += __shfl_down(p, off, 64);
    if ((threadIdx.x & 63) == 0)
        red[threadIdx.x >> 6] = p;
    __syncthreads();
    if (threadIdx.x == 0) {
        const float s = (red[0] + red[1]) + (red[2] + red[3]);
        C[k] = -0.5f * (s + 256.0f * LOG_2PI) + logf(0.1f);
    }
}

// ---------------------------------------------------------------------------
// Main kernel: one thread per row. grid = B/256 blocks x 256 threads.
// logit[b,k] = -0.5 * sum_d q*(iv*q - 2*mu*iv) + C[k]
// then softmax over K and first-occurrence argmax.
// ---------------------------------------------------------------------------
__global__ __launch_bounds__(256) void gmvae_main(
    const float* __restrict__ q_z,
    const float* __restrict__ tab,
    const float* __restrict__ C,
    float* __restrict__ out)
{
    const int row = blockIdx.x * 256 + threadIdx.x;
    const float4* __restrict__ q4 =
        reinterpret_cast<const float4*>(q_z + (size_t)row * DD);
    const float4* __restrict__ t4 = reinterpret_cast<const float4*>(tab);

    float4 acc[KK];
    #pragma unroll
    for (int k = 0; k < KK; ++k) acc[k] = make_float4(0.f, 0.f, 0.f, 0.f);

    for (int i = 0; i < DD / 4; ++i) {
        const float4 q = q4[i];
        #pragma unroll
        for (int k = 0; k < KK; ++k) {
            // uniform (i,k) index -> scalarizable table loads
            const float4 iv = t4[(i * KK + k) * 2];
            const float4 na = t4[(i * KK + k) * 2 + 1];
            acc[k].x = fmaf(q.x, fmaf(iv.x, q.x, na.x), acc[k].x);
            acc[k].y = fmaf(q.y, fmaf(iv.y, q.y, na.y), acc[k].y);
            acc[k].z = fmaf(q.z, fmaf(iv.z, q.z, na.z), acc[k].z);
            acc[k].w = fmaf(q.w, fmaf(iv.w, q.w, na.w), acc[k].w);
        }
    }

    float logit[KK];
    #pragma unroll
    for (int k = 0; k < KK; ++k) {
        const float s = (acc[k].x + acc[k].y) + (acc[k].z + acc[k].w);
        logit[k] = fmaf(s, -0.5f, C[k]);
    }

    float mx = logit[0];
    #pragma unroll
    for (int k = 1; k < KK; ++k) mx = fmaxf(mx, logit[k]);

    float e[KK];
    float sum = 0.f;
    #pragma unroll
    for (int k = 0; k < KK; ++k) { e[k] = expf(logit[k] - mx); sum += e[k]; }
    const float inv = 1.0f / sum;

    int idx = 0;
    float best = logit[0];
    #pragma unroll
    for (int k = 1; k < KK; ++k) {
        if (logit[k] > best) { best = logit[k]; idx = k; }
    }

    float* __restrict__ o1 = out + (size_t)row * KK;               // logits
    float* __restrict__ o2 = out + (size_t)BB * KK + (size_t)row * KK; // q_y
    #pragma unroll
    for (int k = 0; k < KK; ++k) o1[k] = logit[k];
    #pragma unroll
    for (int k = 0; k < KK; ++k) o2[k] = e[k] * inv;
    out[(size_t)2 * BB * KK + row] = (float)idx;                   // ind
}

extern "C" void kernel_launch(void* const* d_in, const int* in_sizes, int n_in,
                              void* d_out, int out_size, void* d_ws, size_t ws_size,
                              hipStream_t stream) {
    const float* q_z    = (const float*)d_in[0];
    const float* mu     = (const float*)d_in[1];
    const float* logvar = (const float*)d_in[2];
    float* out = (float*)d_out;

    float* tab = (float*)d_ws;          // 2*K*D = 5120 floats
    float* C   = tab + 2 * KK * DD;     // 10 floats

    gmvae_prep<<<KK, DD, 0, stream>>>(mu, logvar, tab, C);
    gmvae_main<<<BB / 256, 256, 0, stream>>>(q_z, tab, C, out);
}

// Round 2
// 131.893 us; speedup vs baseline: 1.2696x; 1.2696x over previous
//
#include <hip/hip_runtime.h>
#include <hip/hip_bf16.h>
#include <math.h>

#define BB 65536
#define DD 256
#define KK 10
#define LOG_2PI 1.8378770664093453f

// ---------------------------------------------------------------------------
// Prep kernel: grid = K blocks x D threads.
// Table layout (float4 granularity): for float4-index f = s + 16*j of a row,
//   ivPlane[((j*K + k)*16 + s)]  = iv[d..d+3]        (f4 units)
//   naPlane = ivPlane + 640 f4   = -2*mu*iv[d..d+3]
// so at fixed (j,k) the 16 lanes of a row-group read 256B contiguous, and all
// 4 row-groups of a wave read the SAME 4 cache lines (table is row-invariant).
// Also writes per-component constant C[k].
// ---------------------------------------------------------------------------
__global__ __launch_bounds__(DD) void gmvae_prep(
    const float* __restrict__ mu_table,
    const float* __restrict__ logvar_table,
    float* __restrict__ tab,   // 2*K*D floats (20 KB)
    float* __restrict__ C)     // K floats
{
    const int k = blockIdx.x;
    const int d = threadIdx.x;
    const float lv = logvar_table[k * DD + d];
    const float m  = mu_table[k * DD + d];
    const float iv = expf(-lv);          // exact 1.0 when lv==0
    const float a  = m * iv;

    const int f = d >> 2;        // float4 index within row: 0..63
    const int s = f & 15;        // lane-slot 0..15
    const int j = f >> 4;        // 0..3
    const int c = d & 3;
    const int idx = (((j * KK + k) * 16) + s) * 4 + c;
    tab[idx]        = iv;
    tab[idx + 2560] = -2.0f * a;

    // partial for C_k: mu^2*iv + lv
    float p = fmaf(m, a, lv);

    __shared__ float red[4];
    #pragma unroll
    for (int off = 32; off > 0; off >>= 1)
        p += __shfl_down(p, off, 64);
    if ((threadIdx.x & 63) == 0)
        red[threadIdx.x >> 6] = p;
    __syncthreads();
    if (threadIdx.x == 0) {
        const float s2 = (red[0] + red[1]) + (red[2] + red[3]);
        C[k] = -0.5f * (s2 + 256.0f * LOG_2PI) + logf(0.1f);
    }
}

// ---------------------------------------------------------------------------
// Main kernel: 16 lanes per row (4 rows per wave). grid = B*16/256 blocks.
// Each lane handles float4 indices {s, s+16, s+32, s+48} of its row, then a
// 4-step xor-butterfly reduces the 10 partial sums across the 16-lane group.
// ---------------------------------------------------------------------------
__global__ __launch_bounds__(256) void gmvae_main(
    const float* __restrict__ q_z,
    const float* __restrict__ tab,
    const float* __restrict__ C,
    float* __restrict__ out)
{
    const int tid = blockIdx.x * 256 + threadIdx.x;
    const int row = tid >> 4;
    const int s   = tid & 15;

    const float4* __restrict__ q4 =
        reinterpret_cast<const float4*>(q_z) + (size_t)row * 64 + s;
    const float4* __restrict__ iv4 = reinterpret_cast<const float4*>(tab) + s;
    const float4* __restrict__ na4 = iv4 + 640;

    float acc[KK];
    #pragma unroll
    for (int k = 0; k < KK; ++k) acc[k] = 0.f;

    #pragma unroll
    for (int j = 0; j < 4; ++j) {
        const float4 q = q4[j * 16];
        #pragma unroll
        for (int k = 0; k < KK; ++k) {
            const float4 iv = iv4[(j * KK + k) * 16];
            const float4 na = na4[(j * KK + k) * 16];
            acc[k] = fmaf(q.x, fmaf(iv.x, q.x, na.x), acc[k]);
            acc[k] = fmaf(q.y, fmaf(iv.y, q.y, na.y), acc[k]);
            acc[k] = fmaf(q.z, fmaf(iv.z, q.z, na.z), acc[k]);
            acc[k] = fmaf(q.w, fmaf(iv.w, q.w, na.w), acc[k]);
        }
    }

    // reduce each acc[k] across the 16-lane group (xor masks < 16 stay in-group)
    float logit[KK];
    #pragma unroll
    for (int k = 0; k < KK; ++k) {
        float v = acc[k];
        v += __shfl_xor(v, 1, 64);
        v += __shfl_xor(v, 2, 64);
        v += __shfl_xor(v, 4, 64);
        v += __shfl_xor(v, 8, 64);
        logit[k] = fmaf(v, -0.5f, C[k]);
    }

    float mx = logit[0];
    #pragma unroll
    for (int k = 1; k < KK; ++k) mx = fmaxf(mx, logit[k]);

    float e[KK];
    float sum = 0.f;
    #pragma unroll
    for (int k = 0; k < KK; ++k) { e[k] = expf(logit[k] - mx); sum += e[k]; }
    const float inv = 1.0f / sum;

    int idx = 0;
    float best = logit[0];
    #pragma unroll
    for (int k = 1; k < KK; ++k) {
        if (logit[k] > best) { best = logit[k]; idx = k; }
    }

    if (s == 0) {
        float2* __restrict__ o1 =
            reinterpret_cast<float2*>(out) + (size_t)row * 5;
        float2* __restrict__ o2 =
            reinterpret_cast<float2*>(out + (size_t)BB * KK) + (size_t)row * 5;
        #pragma unroll
        for (int k = 0; k < 5; ++k)
            o1[k] = make_float2(logit[2 * k], logit[2 * k + 1]);
        #pragma unroll
        for (int k = 0; k < 5; ++k)
            o2[k] = make_float2(e[2 * k] * inv, e[2 * k + 1] * inv);
        out[(size_t)2 * BB * KK + row] = (float)idx;
    }
}

extern "C" void kernel_launch(void* const* d_in, const int* in_sizes, int n_in,
                              void* d_out, int out_size, void* d_ws, size_t ws_size,
                              hipStream_t stream) {
    const float* q_z    = (const float*)d_in[0];
    const float* mu     = (const float*)d_in[1];
    const float* logvar = (const float*)d_in[2];
    float* out = (float*)d_out;

    float* tab = (float*)d_ws;          // 2*K*D = 5120 floats
    float* C   = tab + 2 * KK * DD;     // 10 floats

    gmvae_prep<<<KK, DD, 0, stream>>>(mu, logvar, tab, C);
    gmvae_main<<<(BB * 16) / 256, 256, 0, stream>>>(q_z, tab, C, out);
}

// Round 4
// 131.592 us; speedup vs baseline: 1.2725x; 1.0023x over previous
//
#include <hip/hip_runtime.h>
#include <hip/hip_bf16.h>
#include <math.h>

#define BB 65536
#define DD 256
#define KK 10
#define LOG_2PI 1.8378770664093453f

// ---------------------------------------------------------------------------
// Prep kernel: grid = K blocks x D threads.
// Table layout (float4 granularity): for float4-index f = s + 16*j of a row,
//   ivPlane[((j*K + k)*16 + s)]  = iv[d..d+3]        (f4 units)
//   naPlane = ivPlane + 640 f4   = -2*mu*iv[d..d+3]
// At fixed (j,k) the 16 lanes of a group read 256B contiguous, and all 4
// groups of a wave read the SAME 256B (table is row-invariant).
// Also writes per-component constant C[k].
// ---------------------------------------------------------------------------
__global__ __launch_bounds__(DD) void gmvae_prep(
    const float* __restrict__ mu_table,
    const float* __restrict__ logvar_table,
    float* __restrict__ tab,   // 2*K*D floats (20 KB)
    float* __restrict__ C)     // K floats
{
    const int k = blockIdx.x;
    const int d = threadIdx.x;
    const float lv = logvar_table[k * DD + d];
    const float m  = mu_table[k * DD + d];
    const float iv = expf(-lv);          // exact 1.0 when lv==0
    const float a  = m * iv;

    const int f = d >> 2;        // float4 index within row: 0..63
    const int s = f & 15;        // lane-slot 0..15
    const int j = f >> 4;        // 0..3
    const int c = d & 3;
    const int idx = (((j * KK + k) * 16) + s) * 4 + c;
    tab[idx]        = iv;
    tab[idx + 2560] = -2.0f * a;

    // partial for C_k: mu^2*iv + lv
    float p = fmaf(m, a, lv);

    __shared__ float red[4];
    #pragma unroll
    for (int off = 32; off > 0; off >>= 1)
        p += __shfl_down(p, off, 64);
    if ((threadIdx.x & 63) == 0)
        red[threadIdx.x >> 6] = p;
    __syncthreads();
    if (threadIdx.x == 0) {
        const float s2 = (red[0] + red[1]) + (red[2] + red[3]);
        C[k] = -0.5f * (s2 + 256.0f * LOG_2PI) + logf(0.1f);
    }
}

// xor-butterfly step within 32-lane halves via ds_swizzle (BitMode):
// offset = (xor<<10) | 0x1F.  Pattern must be a compile-time constant ->
// non-type template parameter.
template <int PATTERN>
__device__ __forceinline__ float swz_add(float v) {
    return v + __int_as_float(
        __builtin_amdgcn_ds_swizzle(__float_as_int(v), PATTERN));
}

// ---------------------------------------------------------------------------
// Main kernel: 16 lanes per group, each group handles 4 ROWS (row blocking
// amortizes the 80 table loads over 4 rows -> VMEM-issue no longer binds).
// grid = B/4 groups * 16 lanes = 262144 threads = 1024 blocks x 256.
// ---------------------------------------------------------------------------
__global__ __launch_bounds__(256) void gmvae_main(
    const float* __restrict__ q_z,
    const float* __restrict__ tab,
    const float* __restrict__ C,
    float* __restrict__ out)
{
    const int tid = blockIdx.x * 256 + threadIdx.x;
    const int g   = tid >> 4;        // group id: 4 rows each
    const int s   = tid & 15;        // slot within group
    const int r0  = g << 2;          // first row of this group

    const float4* __restrict__ q4  = reinterpret_cast<const float4*>(q_z);
    const float4* __restrict__ iv4 = reinterpret_cast<const float4*>(tab) + s;
    const float4* __restrict__ na4 = iv4 + 640;

    float acc[4][KK];
    #pragma unroll
    for (int r = 0; r < 4; ++r)
        #pragma unroll
        for (int k = 0; k < KK; ++k) acc[r][k] = 0.f;

    #pragma unroll
    for (int j = 0; j < 4; ++j) {
        float4 q[4];
        #pragma unroll
        for (int r = 0; r < 4; ++r)
            q[r] = q4[(size_t)(r0 + r) * 64 + j * 16 + s];
        #pragma unroll
        for (int k = 0; k < KK; ++k) {
            const float4 iv = iv4[(j * KK + k) * 16];
            const float4 na = na4[(j * KK + k) * 16];
            #pragma unroll
            for (int r = 0; r < 4; ++r) {
                acc[r][k] = fmaf(q[r].x, fmaf(iv.x, q[r].x, na.x), acc[r][k]);
                acc[r][k] = fmaf(q[r].y, fmaf(iv.y, q[r].y, na.y), acc[r][k]);
                acc[r][k] = fmaf(q[r].z, fmaf(iv.z, q[r].z, na.z), acc[r][k]);
                acc[r][k] = fmaf(q[r].w, fmaf(iv.w, q[r].w, na.w), acc[r][k]);
            }
        }
    }

    // Butterfly-reduce each acc[r][k] across the 16-lane group; afterwards
    // every lane holds the full sum for all 4 rows. Reuse acc in place.
    #pragma unroll
    for (int r = 0; r < 4; ++r) {
        #pragma unroll
        for (int k = 0; k < KK; ++k) {
            float v = acc[r][k];
            v = swz_add<0x041F>(v);   // xor 1
            v = swz_add<0x081F>(v);   // xor 2
            v = swz_add<0x101F>(v);   // xor 4
            v = swz_add<0x201F>(v);   // xor 8
            acc[r][k] = fmaf(v, -0.5f, C[k]);   // logit
        }
    }

    // Each lane picks row (s & 3) and does that row's softmax/argmax
    // (4 redundant copies per row; divergence-free).
    const int rm = s & 3;
    float l[KK];
    #pragma unroll
    for (int k = 0; k < KK; ++k) {
        float v = acc[0][k];
        v = (rm == 1) ? acc[1][k] : v;
        v = (rm == 2) ? acc[2][k] : v;
        v = (rm == 3) ? acc[3][k] : v;
        l[k] = v;
    }

    float mx = l[0];
    #pragma unroll
    for (int k = 1; k < KK; ++k) mx = fmaxf(mx, l[k]);

    float e[KK];
    float sum = 0.f;
    #pragma unroll
    for (int k = 0; k < KK; ++k) { e[k] = __expf(l[k] - mx); sum += e[k]; }
    const float inv = __builtin_amdgcn_rcpf(sum);

    int idx = 0;
    float best = l[0];
    #pragma unroll
    for (int k = 1; k < KK; ++k) {
        if (l[k] > best) { best = l[k]; idx = k; }
    }

    if (s < 4) {                       // lane s stores row r0+s (rm==s here)
        const int row = r0 + s;
        float2* __restrict__ o1 =
            reinterpret_cast<float2*>(out) + (size_t)row * 5;
        float2* __restrict__ o2 =
            reinterpret_cast<float2*>(out + (size_t)BB * KK) + (size_t)row * 5;
        #pragma unroll
        for (int k = 0; k < 5; ++k)
            o1[k] = make_float2(l[2 * k], l[2 * k + 1]);
        #pragma unroll
        for (int k = 0; k < 5; ++k)
            o2[k] = make_float2(e[2 * k] * inv, e[2 * k + 1] * inv);
        out[(size_t)2 * BB * KK + row] = (float)idx;
    }
}

extern "C" void kernel_launch(void* const* d_in, const int* in_sizes, int n_in,
                              void* d_out, int out_size, void* d_ws, size_t ws_size,
                              hipStream_t stream) {
    const float* q_z    = (const float*)d_in[0];
    const float* mu     = (const float*)d_in[1];
    const float* logvar = (const float*)d_in[2];
    float* out = (float*)d_out;

    float* tab = (float*)d_ws;          // 2*K*D = 5120 floats
    float* C   = tab + 2 * KK * DD;     // 10 floats

    gmvae_prep<<<KK, DD, 0, stream>>>(mu, logvar, tab, C);
    gmvae_main<<<(BB / 4) * 16 / 256, 256, 0, stream>>>(q_z, tab, C, out);
}